// Round 9
// baseline (232.571 us; speedup 1.0000x reference)
//
#include <hip/hip_runtime.h>
#include <hip/hip_bf16.h>

#define IN_FEATS 602
#define N_HIDDEN 256
#define N_CLASSES 41
#define N_SRC0 292864
#define N_DST0 11264
#define N_DST1 1024
#define FAN0 25
#define FAN1 10
#define KPAD 1216            // 1204 rounded up to multiple of 64

typedef __attribute__((ext_vector_type(4))) float f32x4;
typedef __attribute__((ext_vector_type(8))) short bf16x8;   // 8 bf16 = 4 VGPRs

// round-to-nearest-even f32 -> bf16, packed pair
static __device__ __forceinline__ unsigned pack_bf16x2(float lo, float hi) {
    unsigned a = __float_as_uint(lo);
    unsigned b = __float_as_uint(hi);
    a = (a + 0x7fffu + ((a >> 16) & 1u)) >> 16;
    b = (b + 0x7fffu + ((b >> 16) & 1u)) >> 16;
    return (a & 0xffffu) | (b << 16);
}

// ---------------------------------------------------------------------------
// Kernel 1: build A[d] = [ bf16(x[d]) (602) | bf16(mean_25 x[idx]) (602) | 0 pad ]
// One wave per dst (4 dsts/block). NEW vs R8: each wave visits its 25
// neighbor rows in ASCENDING ADDRESS ORDER (rank-sort via LDS). Since ~80%
// of all dst-waves are co-resident, sorted order phase-locks the whole
// machine to a narrow address band (~order-statistic spread, L3-sized), so
// the ~242 MB of duplicate row reads hit L3 instead of HBM, and the DRAM
// request stream is address-clustered.
// ---------------------------------------------------------------------------
__global__ __launch_bounds__(256) void agg0_kernel(
    const float* __restrict__ x,
    const int* __restrict__ idx,
    __hip_bfloat16* __restrict__ A)
{
    const int wave = threadIdx.x >> 6;
    const int lane = threadIdx.x & 63;
    const int d = blockIdx.x * 4 + wave;

    __shared__ int sidx[4][FAN0];
    __shared__ int ssrt[4][FAN0];
    if (lane < FAN0) sidx[wave][lane] = idx[d * FAN0 + lane];
    __syncthreads();
    if (lane < FAN0) {
        const int v = sidx[wave][lane];
        int rank = 0;
        #pragma unroll
        for (int j = 0; j < FAN0; ++j) {
            const int u = sidx[wave][j];
            rank += (u < v) || (u == v && j < lane);
        }
        ssrt[wave][rank] = v;
    }
    __syncthreads();

    unsigned* Arow = (unsigned*)(A + (size_t)d * KPAD);
    const float* xself = x + (size_t)d * IN_FEATS;

    // zero pad cols 1204..1215 (uint slots 602..607)
    if (lane < 6) Arow[602 + lane] = 0u;

    float accx[5], accy[5];
    #pragma unroll
    for (int c = 0; c < 5; ++c) { accx[c] = 0.f; accy[c] = 0.f; }

    #pragma unroll 5
    for (int n = 0; n < FAN0; ++n) {
        const float* xr = x + (size_t)ssrt[wave][n] * IN_FEATS;
        #pragma unroll
        for (int c = 0; c < 5; ++c) {
            const int f = c * 128 + lane * 2;
            if (f < IN_FEATS) {
                const float2 v = *(const float2*)&xr[f];
                accx[c] += v.x; accy[c] += v.y;
            }
        }
    }

    #pragma unroll
    for (int c = 0; c < 5; ++c) {
        const int f = c * 128 + lane * 2;
        if (f < IN_FEATS) {
            const int f2 = f >> 1;
            const float2 sv = *(const float2*)&xself[f];
            Arow[f2] = pack_bf16x2(sv.x, sv.y);
            // neigh half starts at element 602 -> byte 1204 (4-B aligned)
            *(unsigned*)((char*)Arow + 1204 + f2 * 4) =
                pack_bf16x2(accx[c] * (1.0f / FAN0), accy[c] * (1.0f / FAN0));
        }
    }
}

// ---------------------------------------------------------------------------
// Kernel 2: Wt[n][k] = bf16( k<602 ? Wself0[k][n] : k<1204 ? Wneigh0[k-602][n] : 0 )
// Wt is [N_HIDDEN][KPAD] bf16. (verified R2)
// ---------------------------------------------------------------------------
__global__ __launch_bounds__(256) void wprep_kernel(
    const float* __restrict__ Ws,
    const float* __restrict__ Wn,
    __hip_bfloat16* __restrict__ Wt)
{
    __shared__ float tile[32][33];
    const int k0 = blockIdx.x * 32, n0 = blockIdx.y * 32;
    const int tx = threadIdx.x & 31, ty = threadIdx.x >> 5;   // 32 x 8

    #pragma unroll
    for (int i = 0; i < 4; ++i) {
        const int k = k0 + ty + i * 8;
        const int n = n0 + tx;
        float v = 0.f;
        if (k < IN_FEATS)            v = Ws[(size_t)k * N_HIDDEN + n];
        else if (k < 2 * IN_FEATS)   v = Wn[(size_t)(k - IN_FEATS) * N_HIDDEN + n];
        tile[ty + i * 8][tx] = v;
    }
    __syncthreads();
    #pragma unroll
    for (int i = 0; i < 4; ++i) {
        const int n = n0 + ty + i * 8;
        const int k = k0 + tx;
        Wt[(size_t)n * KPAD + k] = __float2bfloat16(tile[tx][ty + i * 8]);
    }
}

// ---------------------------------------------------------------------------
// Kernel 3: h = relu(A @ Wt^T + b0) via bf16 MFMA. (verified R2: 64x64, BK=64)
// ---------------------------------------------------------------------------
#define BKK 64
#define LDSW 72

__global__ __launch_bounds__(256) void gemm0_mfma(
    const __hip_bfloat16* __restrict__ A,     // [N_DST0][KPAD]
    const __hip_bfloat16* __restrict__ Wt,    // [N_HIDDEN][KPAD]
    const float* __restrict__ bias,           // [256]
    float* __restrict__ h)                    // [N_DST0][256]
{
    __shared__ __hip_bfloat16 As[64 * LDSW];
    __shared__ __hip_bfloat16 Bs[64 * LDSW];

    const int tid  = threadIdx.x;
    const int lane = tid & 63;
    const int wave = tid >> 6;
    const int wm = wave >> 1, wn = wave & 1;    // 2x2 waves of 32x32
    const int g = lane >> 4, r = lane & 15;
    const int m0 = blockIdx.y * 64, n0 = blockIdx.x * 64;

    const int srow = tid >> 2;
    const int sc   = (tid & 3) * 16;

    const size_t a_off = (size_t)(m0 + srow) * KPAD + sc;
    const size_t b_off = (size_t)(n0 + srow) * KPAD + sc;

    f32x4 acc[2][2] = {};

    for (int k0 = 0; k0 < KPAD; k0 += BKK) {
        *(float4*)&As[srow * LDSW + sc]     = *(const float4*)&A[a_off + k0];
        *(float4*)&As[srow * LDSW + sc + 8] = *(const float4*)&A[a_off + k0 + 8];
        *(float4*)&Bs[srow * LDSW + sc]     = *(const float4*)&Wt[b_off + k0];
        *(float4*)&Bs[srow * LDSW + sc + 8] = *(const float4*)&Wt[b_off + k0 + 8];
        __syncthreads();

        #pragma unroll
        for (int kh = 0; kh < 2; ++kh) {
            const bf16x8 af0 = *(const bf16x8*)&As[(wm * 32 +      r) * LDSW + kh * 32 + g * 8];
            const bf16x8 af1 = *(const bf16x8*)&As[(wm * 32 + 16 + r) * LDSW + kh * 32 + g * 8];
            const bf16x8 bf0 = *(const bf16x8*)&Bs[(wn * 32 +      r) * LDSW + kh * 32 + g * 8];
            const bf16x8 bf1 = *(const bf16x8*)&Bs[(wn * 32 + 16 + r) * LDSW + kh * 32 + g * 8];

            acc[0][0] = __builtin_amdgcn_mfma_f32_16x16x32_bf16(af0, bf0, acc[0][0], 0, 0, 0);
            acc[0][1] = __builtin_amdgcn_mfma_f32_16x16x32_bf16(af0, bf1, acc[0][1], 0, 0, 0);
            acc[1][0] = __builtin_amdgcn_mfma_f32_16x16x32_bf16(af1, bf0, acc[1][0], 0, 0, 0);
            acc[1][1] = __builtin_amdgcn_mfma_f32_16x16x32_bf16(af1, bf1, acc[1][1], 0, 0, 0);
        }
        __syncthreads();
    }

    // C/D layout (m89-verified): col = lane&15, row = (lane>>4)*4 + j
    #pragma unroll
    for (int mh = 0; mh < 2; ++mh)
        #pragma unroll
        for (int nh = 0; nh < 2; ++nh) {
            const int col = n0 + wn * 32 + nh * 16 + r;
            const float bv = bias[col];
            #pragma unroll
            for (int j = 0; j < 4; ++j) {
                const int row = m0 + wm * 32 + mh * 16 + g * 4 + j;
                const float v = acc[mh][nh][j] + bv;
                h[(size_t)row * N_HIDDEN + col] = fmaxf(v, 0.f);
            }
        }
}

// ---------------------------------------------------------------------------
// Kernel 4: out[d] = h[d]@Ws1 + (mean_10 h[idx1])@Wn1 + b1.  4 dsts/block.
// (verified R5)
// ---------------------------------------------------------------------------
__global__ __launch_bounds__(256) void tail_kernel(
    const float* __restrict__ h,
    const int* __restrict__ idx1,
    const float* __restrict__ Ws,     // [256][41]
    const float* __restrict__ Wn,     // [256][41]
    const float* __restrict__ b,      // [41]
    float* __restrict__ out)          // [1024][41]
{
    const int w = threadIdx.x >> 6;
    const int lane = threadIdx.x & 63;
    const int d = blockIdx.x * 4 + w;

    __shared__ float hd[4][N_HIDDEN];
    __shared__ float hn[4][N_HIDDEN];
    __shared__ int sidx[4][FAN1];
    if (lane < FAN1) sidx[w][lane] = idx1[d * FAN1 + lane];
    __syncthreads();

    {
        const int k0 = lane * 4;
        const float4 self = *(const float4*)&h[(size_t)d * N_HIDDEN + k0];
        float ax = 0.f, ay = 0.f, az = 0.f, aw = 0.f;
        #pragma unroll
        for (int i = 0; i < FAN1; ++i) {
            const float4 v = *(const float4*)&h[(size_t)sidx[w][i] * N_HIDDEN + k0];
            ax += v.x; ay += v.y; az += v.z; aw += v.w;
        }
        *(float4*)&hd[w][k0] = self;
        hn[w][k0 + 0] = ax * (1.0f / FAN1);
        hn[w][k0 + 1] = ay * (1.0f / FAN1);
        hn[w][k0 + 2] = az * (1.0f / FAN1);
        hn[w][k0 + 3] = aw * (1.0f / FAN1);
    }
    __syncthreads();

    if (lane < N_CLASSES) {
        const int n = lane;
        float a0 = b[n], a1 = 0.f, a2 = 0.f, a3 = 0.f;
        #pragma unroll 4
        for (int k = 0; k < N_HIDDEN; k += 4) {
            a0 += hd[w][k + 0] * Ws[(k + 0) * N_CLASSES + n] + hn[w][k + 0] * Wn[(k + 0) * N_CLASSES + n];
            a1 += hd[w][k + 1] * Ws[(k + 1) * N_CLASSES + n] + hn[w][k + 1] * Wn[(k + 1) * N_CLASSES + n];
            a2 += hd[w][k + 2] * Ws[(k + 2) * N_CLASSES + n] + hn[w][k + 2] * Wn[(k + 2) * N_CLASSES + n];
            a3 += hd[w][k + 3] * Ws[(k + 3) * N_CLASSES + n] + hn[w][k + 3] * Wn[(k + 3) * N_CLASSES + n];
        }
        out[(size_t)d * N_CLASSES + n] = a0 + a1 + a2 + a3;
    }
}

// ---------------------------------------------------------------------------
extern "C" void kernel_launch(void* const* d_in, const int* in_sizes, int n_in,
                              void* d_out, int out_size, void* d_ws, size_t ws_size,
                              hipStream_t stream) {
    const float* x       = (const float*)d_in[0];
    const float* Wself0  = (const float*)d_in[1];
    const float* Wneigh0 = (const float*)d_in[2];
    const float* b0      = (const float*)d_in[3];
    const float* Wself1  = (const float*)d_in[4];
    const float* Wneigh1 = (const float*)d_in[5];
    const float* b1      = (const float*)d_in[6];
    const int*   idx0    = (const int*)d_in[7];
    const int*   idx1    = (const int*)d_in[8];
    float* out = (float*)d_out;

    // ws layout: A bf16 [11264*1216] | Wt bf16 [256*1216] | h f32 [11264*256]
    __hip_bfloat16* Abf = (__hip_bfloat16*)d_ws;
    __hip_bfloat16* Wt  = Abf + (size_t)N_DST0 * KPAD;
    float*          h   = (float*)(Wt + (size_t)N_HIDDEN * KPAD);

    wprep_kernel<<<dim3(KPAD / 32, N_HIDDEN / 32), 256, 0, stream>>>(Wself0, Wneigh0, Wt);
    agg0_kernel<<<N_DST0 / 4, 256, 0, stream>>>(x, idx0, Abf);
    gemm0_mfma<<<dim3(N_HIDDEN / 64, N_DST0 / 64), 256, 0, stream>>>(Abf, Wt, b0, h);
    tail_kernel<<<N_DST1 / 4, 256, 0, stream>>>(h, idx1, Wself1, Wneigh1, b1, out);
}

// Round 10
// 214.779 us; speedup vs baseline: 1.0828x; 1.0828x over previous
//
#include <hip/hip_runtime.h>
#include <hip/hip_bf16.h>

#define IN_FEATS 602
#define N_HIDDEN 256
#define N_CLASSES 41
#define N_SRC0 292864
#define N_DST0 11264
#define N_DST1 1024
#define FAN0 25
#define FAN1 10
#define KPAD 1216            // 1204 rounded up to multiple of 64
#define NAGG (N_DST0 / 4)    // 2816 agg blocks
#define NWP ((KPAD / 32) * (N_HIDDEN / 32))   // 304 wprep blocks

typedef __attribute__((ext_vector_type(4))) float f32x4;
typedef __attribute__((ext_vector_type(8))) short bf16x8;   // 8 bf16 = 4 VGPRs

// round-to-nearest-even f32 -> bf16, packed pair
static __device__ __forceinline__ unsigned pack_bf16x2(float lo, float hi) {
    unsigned a = __float_as_uint(lo);
    unsigned b = __float_as_uint(hi);
    a = (a + 0x7fffu + ((a >> 16) & 1u)) >> 16;
    b = (b + 0x7fffu + ((b >> 16) & 1u)) >> 16;
    return (a & 0xffffu) | (b << 16);
}

// ---------------------------------------------------------------------------
// Kernel 1 (combo): blocks [0,NAGG) build A rows (gather+mean+bf16 pack,
// R8-verified body); blocks [NAGG, NAGG+NWP) transpose W into Wt
// (R2-verified body). Outputs are independent -> dispatch-order-safe.
// ---------------------------------------------------------------------------
__global__ __launch_bounds__(256) void prep_kernel(
    const float* __restrict__ x,
    const int* __restrict__ idx,
    const float* __restrict__ Ws,
    const float* __restrict__ Wn,
    __hip_bfloat16* __restrict__ A,
    __hip_bfloat16* __restrict__ Wt)
{
    __shared__ __align__(16) char sm[32 * 33 * 4];   // 4.2 KB (wprep tile / agg sidx)

    if (blockIdx.x < NAGG) {
        // ---- agg role ----
        int (*sidx)[FAN0] = (int(*)[FAN0])sm;
        const int wave = threadIdx.x >> 6;
        const int lane = threadIdx.x & 63;
        const int d = blockIdx.x * 4 + wave;

        if (lane < FAN0) sidx[wave][lane] = idx[d * FAN0 + lane];
        __syncthreads();

        unsigned* Arow = (unsigned*)(A + (size_t)d * KPAD);
        const float* xself = x + (size_t)d * IN_FEATS;

        if (lane < 6) Arow[602 + lane] = 0u;   // zero pad cols 1204..1215

        float accx[5], accy[5];
        #pragma unroll
        for (int c = 0; c < 5; ++c) { accx[c] = 0.f; accy[c] = 0.f; }

        #pragma unroll 5
        for (int n = 0; n < FAN0; ++n) {
            const float* xr = x + (size_t)sidx[wave][n] * IN_FEATS;
            #pragma unroll
            for (int c = 0; c < 5; ++c) {
                const int f = c * 128 + lane * 2;
                if (f < IN_FEATS) {
                    const float2 v = *(const float2*)&xr[f];
                    accx[c] += v.x; accy[c] += v.y;
                }
            }
        }

        #pragma unroll
        for (int c = 0; c < 5; ++c) {
            const int f = c * 128 + lane * 2;
            if (f < IN_FEATS) {
                const int f2 = f >> 1;
                const float2 sv = *(const float2*)&xself[f];
                Arow[f2] = pack_bf16x2(sv.x, sv.y);
                *(unsigned*)((char*)Arow + 1204 + f2 * 4) =
                    pack_bf16x2(accx[c] * (1.0f / FAN0), accy[c] * (1.0f / FAN0));
            }
        }
    } else {
        // ---- wprep role ----
        float (*tile)[33] = (float(*)[33])sm;
        const int b = blockIdx.x - NAGG;
        const int k0 = (b % (KPAD / 32)) * 32;
        const int n0 = (b / (KPAD / 32)) * 32;
        const int tx = threadIdx.x & 31, ty = threadIdx.x >> 5;   // 32 x 8

        #pragma unroll
        for (int i = 0; i < 4; ++i) {
            const int k = k0 + ty + i * 8;
            const int n = n0 + tx;
            float v = 0.f;
            if (k < IN_FEATS)            v = Ws[(size_t)k * N_HIDDEN + n];
            else if (k < 2 * IN_FEATS)   v = Wn[(size_t)(k - IN_FEATS) * N_HIDDEN + n];
            tile[ty + i * 8][tx] = v;
        }
        __syncthreads();
        #pragma unroll
        for (int i = 0; i < 4; ++i) {
            const int n = n0 + ty + i * 8;
            const int k = k0 + tx;
            Wt[(size_t)n * KPAD + k] = __float2bfloat16(tile[tx][ty + i * 8]);
        }
    }
}

// ---------------------------------------------------------------------------
// Kernel 2: h = relu(A @ Wt^T + b0) via bf16 MFMA.
// 64x64 tile, BK=64, 4 waves of 32x32. NEW vs R9:
//  - double-buffered LDS, ONE barrier per K-step (loads for t+1 issued
//    before MFMA of t; write to buf^1 after MFMA — hazard-free since every
//    thread's reads of buf[cur] precede the barrier of step t+1).
//  - XCD-swizzled block id: the 4 N-blocks sharing the same A rows map to
//    the same XCD (dispatch id % 8) -> A re-reads hit that XCD's L2.
// ---------------------------------------------------------------------------
#define BKK 64
#define LDSW 72

__global__ __launch_bounds__(256) void gemm0_mfma(
    const __hip_bfloat16* __restrict__ A,     // [N_DST0][KPAD]
    const __hip_bfloat16* __restrict__ Wt,    // [N_HIDDEN][KPAD]
    const float* __restrict__ bias,           // [256]
    float* __restrict__ h)                    // [N_DST0][256]
{
    __shared__ __hip_bfloat16 As[2][64 * LDSW];
    __shared__ __hip_bfloat16 Bs[2][64 * LDSW];

    // de-swizzle: D = s + 8*(bx + 4*q), by = 8*q + s  (bijective, 704 blocks)
    const int D = blockIdx.x;
    const int s = D & 7;
    const int e = D >> 3;
    const int bx = e & 3;
    const int by = 8 * (e >> 2) + s;

    const int tid  = threadIdx.x;
    const int lane = tid & 63;
    const int wave = tid >> 6;
    const int wm = wave >> 1, wn = wave & 1;    // 2x2 waves of 32x32
    const int g = lane >> 4, r = lane & 15;
    const int m0 = by * 64, n0 = bx * 64;

    const int srow = tid >> 2;
    const int sc   = (tid & 3) * 16;
    const int sbase = srow * LDSW + sc;

    const size_t a_off = (size_t)(m0 + srow) * KPAD + sc;
    const size_t b_off = (size_t)(n0 + srow) * KPAD + sc;

    f32x4 acc[2][2] = {};

    float4 ra0, ra1, rb0, rb1;
    ra0 = *(const float4*)&A[a_off];      ra1 = *(const float4*)&A[a_off + 8];
    rb0 = *(const float4*)&Wt[b_off];     rb1 = *(const float4*)&Wt[b_off + 8];
    *(float4*)&As[0][sbase] = ra0;  *(float4*)&As[0][sbase + 8] = ra1;
    *(float4*)&Bs[0][sbase] = rb0;  *(float4*)&Bs[0][sbase + 8] = rb1;

    const int NT = KPAD / BKK;   // 19
    for (int t = 0; t < NT; ++t) {
        __syncthreads();
        const int cur = t & 1;

        if (t + 1 < NT) {
            const size_t k1 = (size_t)(t + 1) * BKK;
            ra0 = *(const float4*)&A[a_off + k1];      ra1 = *(const float4*)&A[a_off + k1 + 8];
            rb0 = *(const float4*)&Wt[b_off + k1];     rb1 = *(const float4*)&Wt[b_off + k1 + 8];
        }

        #pragma unroll
        for (int kh = 0; kh < 2; ++kh) {
            const bf16x8 af0 = *(const bf16x8*)&As[cur][(wm * 32 +      r) * LDSW + kh * 32 + g * 8];
            const bf16x8 af1 = *(const bf16x8*)&As[cur][(wm * 32 + 16 + r) * LDSW + kh * 32 + g * 8];
            const bf16x8 bf0 = *(const bf16x8*)&Bs[cur][(wn * 32 +      r) * LDSW + kh * 32 + g * 8];
            const bf16x8 bf1 = *(const bf16x8*)&Bs[cur][(wn * 32 + 16 + r) * LDSW + kh * 32 + g * 8];

            acc[0][0] = __builtin_amdgcn_mfma_f32_16x16x32_bf16(af0, bf0, acc[0][0], 0, 0, 0);
            acc[0][1] = __builtin_amdgcn_mfma_f32_16x16x32_bf16(af0, bf1, acc[0][1], 0, 0, 0);
            acc[1][0] = __builtin_amdgcn_mfma_f32_16x16x32_bf16(af1, bf0, acc[1][0], 0, 0, 0);
            acc[1][1] = __builtin_amdgcn_mfma_f32_16x16x32_bf16(af1, bf1, acc[1][1], 0, 0, 0);
        }

        if (t + 1 < NT) {
            const int nxt = cur ^ 1;
            *(float4*)&As[nxt][sbase] = ra0;  *(float4*)&As[nxt][sbase + 8] = ra1;
            *(float4*)&Bs[nxt][sbase] = rb0;  *(float4*)&Bs[nxt][sbase + 8] = rb1;
        }
    }

    // C/D layout (m89-verified): col = lane&15, row = (lane>>4)*4 + j
    #pragma unroll
    for (int mh = 0; mh < 2; ++mh)
        #pragma unroll
        for (int nh = 0; nh < 2; ++nh) {
            const int col = n0 + wn * 32 + nh * 16 + r;
            const float bv = bias[col];
            #pragma unroll
            for (int j = 0; j < 4; ++j) {
                const int row = m0 + wm * 32 + mh * 16 + g * 4 + j;
                const float v = acc[mh][nh][j] + bv;
                h[(size_t)row * N_HIDDEN + col] = fmaxf(v, 0.f);
            }
        }
}

// ---------------------------------------------------------------------------
// Kernel 3: out[d] = h[d]@Ws1 + (mean_10 h[idx1])@Wn1 + b1.  4 dsts/block.
// (verified R5)
// ---------------------------------------------------------------------------
__global__ __launch_bounds__(256) void tail_kernel(
    const float* __restrict__ h,
    const int* __restrict__ idx1,
    const float* __restrict__ Ws,     // [256][41]
    const float* __restrict__ Wn,     // [256][41]
    const float* __restrict__ b,      // [41]
    float* __restrict__ out)          // [1024][41]
{
    const int w = threadIdx.x >> 6;
    const int lane = threadIdx.x & 63;
    const int d = blockIdx.x * 4 + w;

    __shared__ float hd[4][N_HIDDEN];
    __shared__ float hn[4][N_HIDDEN];
    __shared__ int sidx[4][FAN1];
    if (lane < FAN1) sidx[w][lane] = idx1[d * FAN1 + lane];
    __syncthreads();

    {
        const int k0 = lane * 4;
        const float4 self = *(const float4*)&h[(size_t)d * N_HIDDEN + k0];
        float ax = 0.f, ay = 0.f, az = 0.f, aw = 0.f;
        #pragma unroll
        for (int i = 0; i < FAN1; ++i) {
            const float4 v = *(const float4*)&h[(size_t)sidx[w][i] * N_HIDDEN + k0];
            ax += v.x; ay += v.y; az += v.z; aw += v.w;
        }
        *(float4*)&hd[w][k0] = self;
        hn[w][k0 + 0] = ax * (1.0f / FAN1);
        hn[w][k0 + 1] = ay * (1.0f / FAN1);
        hn[w][k0 + 2] = az * (1.0f / FAN1);
        hn[w][k0 + 3] = aw * (1.0f / FAN1);
    }
    __syncthreads();

    if (lane < N_CLASSES) {
        const int n = lane;
        float a0 = b[n], a1 = 0.f, a2 = 0.f, a3 = 0.f;
        #pragma unroll 4
        for (int k = 0; k < N_HIDDEN; k += 4) {
            a0 += hd[w][k + 0] * Ws[(k + 0) * N_CLASSES + n] + hn[w][k + 0] * Wn[(k + 0) * N_CLASSES + n];
            a1 += hd[w][k + 1] * Ws[(k + 1) * N_CLASSES + n] + hn[w][k + 1] * Wn[(k + 1) * N_CLASSES + n];
            a2 += hd[w][k + 2] * Ws[(k + 2) * N_CLASSES + n] + hn[w][k + 2] * Wn[(k + 2) * N_CLASSES + n];
            a3 += hd[w][k + 3] * Ws[(k + 3) * N_CLASSES + n] + hn[w][k + 3] * Wn[(k + 3) * N_CLASSES + n];
        }
        out[(size_t)d * N_CLASSES + n] = a0 + a1 + a2 + a3;
    }
}

// ---------------------------------------------------------------------------
extern "C" void kernel_launch(void* const* d_in, const int* in_sizes, int n_in,
                              void* d_out, int out_size, void* d_ws, size_t ws_size,
                              hipStream_t stream) {
    const float* x       = (const float*)d_in[0];
    const float* Wself0  = (const float*)d_in[1];
    const float* Wneigh0 = (const float*)d_in[2];
    const float* b0      = (const float*)d_in[3];
    const float* Wself1  = (const float*)d_in[4];
    const float* Wneigh1 = (const float*)d_in[5];
    const float* b1      = (const float*)d_in[6];
    const int*   idx0    = (const int*)d_in[7];
    const int*   idx1    = (const int*)d_in[8];
    float* out = (float*)d_out;

    // ws layout: A bf16 [11264*1216] | Wt bf16 [256*1216] | h f32 [11264*256]
    __hip_bfloat16* Abf = (__hip_bfloat16*)d_ws;
    __hip_bfloat16* Wt  = Abf + (size_t)N_DST0 * KPAD;
    float*          h   = (float*)(Wt + (size_t)N_HIDDEN * KPAD);

    prep_kernel<<<NAGG + NWP, 256, 0, stream>>>(x, idx0, Wself0, Wneigh0, Abf, Wt);
    gemm0_mfma<<<(N_HIDDEN / 64) * (N_DST0 / 64), 256, 0, stream>>>(Abf, Wt, b0, h);
    tail_kernel<<<N_DST1 / 4, 256, 0, stream>>>(h, idx1, Wself1, Wneigh1, b1, out);
}